// Round 4
// baseline (651.998 us; speedup 1.0000x reference)
//
#include <hip/hip_runtime.h>

// Problem constants (fixed by setup_inputs)
#define BB 8
#define SS 16
#define HH 512
#define WW 512
#define HWP (HH*WW)

// kC tiling
#define TH 16
#define TW 32
#define HR 18          // halo rows
#define HC 34          // halo cols
#define NH (HR*HC)     // 612 halo elements
#define LW 35          // padded LDS row stride

// workspace layout (float offsets)
#define WS_MSUM 0      // [8][16]
#define WS_FSUM 128    // [8][16][2]
#define WS_MEAN 384    // [8][16][2]
#define WS_ACC  640    // num_s[16], l1x, l1y, l2x, l2y  (20 floats)
#define WS_TOTAL 660

__device__ __forceinline__ float clip01(float x){ return fminf(fmaxf(x, 0.0f), 1.0f); }
__device__ __forceinline__ float pow045(float v){ return exp2f(0.45f * log2f(v)); }
__device__ __forceinline__ float cbn(float x){ return pow045(x*x + 1e-6f); }

// ---------------- kernel A: mask sums + mask-weighted flow sums ----------------
// 4 waves/block; wave w owns segments 4w..4w+3 (12 accumulators/wave -> low VGPR,
// deep load pipelining). Each wave streams the block's 512-pixel chunk; flow
// re-reads by waves 1..3 hit L1/L2.
__global__ __launch_bounds__(256, 4)
void kA(const float* __restrict__ flow, const float* __restrict__ masks,
        float* __restrict__ ws)
{
    const int b    = blockIdx.y;
    const int wv   = threadIdx.x >> 6;     // 0..3
    const int lane = threadIdx.x & 63;
    const int s0   = wv * 4;

    const float* fU = flow + (size_t)b * 2 * HWP;
    const float* fV = fU + HWP;
    const float* mb = masks + (size_t)b * SS * HWP + (size_t)s0 * HWP;

    float acc[12];
#pragma unroll
    for (int i = 0; i < 12; ++i) acc[i] = 0.f;

#pragma unroll
    for (int step = 0; step < 2; ++step){
        const int p = blockIdx.x * 512 + step * 256 + lane * 4;
        const float4 u = *reinterpret_cast<const float4*>(fU + p);
        const float4 v = *reinterpret_cast<const float4*>(fV + p);
#pragma unroll
        for (int k = 0; k < 4; ++k){
            const float4 m = *reinterpret_cast<const float4*>(mb + (size_t)k * HWP + p);
            acc[3*k  ] += (m.x + m.y) + (m.z + m.w);
            acc[3*k+1] += m.x*u.x + m.y*u.y + m.z*u.z + m.w*u.w;
            acc[3*k+2] += m.x*v.x + m.y*v.y + m.z*v.z + m.w*v.w;
        }
    }

#pragma unroll
    for (int i = 0; i < 12; ++i){
#pragma unroll
        for (int o = 32; o > 0; o >>= 1) acc[i] += __shfl_down(acc[i], o, 64);
    }
    if (lane == 0){
#pragma unroll
        for (int k = 0; k < 4; ++k){
            const int s = s0 + k;
            atomicAdd(ws + WS_MSUM + b*SS + s,           acc[3*k  ]);
            atomicAdd(ws + WS_FSUM + (b*SS + s)*2 + 0,   acc[3*k+1]);
            atomicAdd(ws + WS_FSUM + (b*SS + s)*2 + 1,   acc[3*k+2]);
        }
    }
}

// ---------------- kernel B: mean_flow = fsum / max(msum, 1e-6) ----------------
__global__ void kB(float* __restrict__ ws)
{
    const int i = threadIdx.x;            // 256 = 8*16*2
    const int bs = i >> 1;
    const float ms = fmaxf(ws[WS_MSUM + bs], 1e-6f);
    ws[WS_MEAN + i] = ws[WS_FSUM + i] / ms;
}

// ---------------- kernel C: fused boundary/edge/smooth/variance pass ----------------
// 1D grid 4096, XCD-slab remap: XCD k processes batch k's tiles contiguously
// (halo sharing in XCD-local L2). 2-deep mask prefetch (pf, pg): segment s+3
// loaded at iter s, written at iter s+2 -> 2 iterations of latency slack.
__global__ __launch_bounds__(256, 2)
void kC(const float* __restrict__ flow, const float* __restrict__ image,
        const float* __restrict__ masks, float* __restrict__ ws)
{
    const int lin = blockIdx.x;                   // 0..4095
    const int wg  = (lin & 7) * 512 + (lin >> 3); // XCD-contiguous slabs (4096%8==0, bijective)
    const int b   = wg >> 9;
    const int rem = wg & 511;
    const int h0  = (rem >> 4) * TH;
    const int w0  = (rem & 15) * TW;
    const int tid = threadIdx.x;

    __shared__ float sImg[3][HR*LW];
    __shared__ float sFlo[2][HR*LW];
    __shared__ float sOcc[HR*LW];
    __shared__ float sMsk[2][HR*LW];
    __shared__ float sMean[2*SS];
    __shared__ float sRed[4][20];

    if (tid < 2*SS) sMean[tid] = ws[WS_MEAN + b*2*SS + tid];

    // halo slot ownership: k=0,1 always valid; k=2 only for tid<100 (612 slots)
    int hli[3], cgi[3]; bool hval[3]; bool hin[3]; int hgi[3];
#pragma unroll
    for (int k = 0; k < 3; ++k){
        const int idx = tid + k*256;
        hval[k] = (k < 2) || (tid < NH - 512);
        const int r = idx / HC, c = idx % HC;
        const int gh = h0 - 1 + r, gw = w0 - 1 + c;
        hli[k] = r*LW + c;
        hin[k] = ((unsigned)gh < (unsigned)HH) && ((unsigned)gw < (unsigned)WW);
        hgi[k] = gh*WW + gw;
        const int ch_ = min(max(gh, 0), HH-1);
        const int cw_ = min(max(gw, 0), WW-1);
        cgi[k] = ch_*WW + cw_;
    }

    const float* img = image + (size_t)b * 3 * HWP;
    const float* flo = flow  + (size_t)b * 2 * HWP;
    const float* mb  = masks + (size_t)b * SS * HWP;

    // image (zero-pad) + flow
#pragma unroll
    for (int k = 0; k < 3; ++k){
        if (hval[k]){
            const bool in = hin[k]; const int gi = hgi[k]; const int li = hli[k];
            sImg[0][li] = in ? img[0*HWP + gi] : 0.f;
            sImg[1][li] = in ? img[1*HWP + gi] : 0.f;
            sImg[2][li] = in ? img[2*HWP + gi] : 0.f;
            sFlo[0][li] = in ? flo[0*HWP + gi] : 0.f;
            sFlo[1][li] = in ? flo[1*HWP + gi] : 0.f;
        }
    }

    float occA[3] = {0.f, 0.f, 0.f};
    float pf[3], pg[3], t0[3];

    // prologue: s=0 load+write, s=1 -> pf, s=2 -> pg
#pragma unroll
    for (int k = 0; k < 3; ++k) if (hval[k]) t0[k] = mb[cgi[k]];
#pragma unroll
    for (int k = 0; k < 3; ++k) if (hval[k]){ sMsk[0][hli[k]] = t0[k]; occA[k] += t0[k]; }
#pragma unroll
    for (int k = 0; k < 3; ++k) if (hval[k]) pf[k] = mb[1*HWP + cgi[k]];
#pragma unroll
    for (int k = 0; k < 3; ++k) if (hval[k]) pg[k] = mb[2*HWP + cgi[k]];
    __syncthreads();

    // pixel assignment: 2 horizontally adjacent pixels per thread
    const int pr  = tid >> 4;          // 0..15 tile row
    const int pc2 = (tid & 15) << 1;   // 0,2,..,30 tile col of pixel0
    const int R = pr + 1;
    const float fu0 = sFlo[0][R*LW + pc2+1], fu1 = sFlo[0][R*LW + pc2+2];
    const float fv0 = sFlo[1][R*LW + pc2+1], fv1 = sFlo[1][R*LW + pc2+2];

    float numv[SS];
    float perS0 = 0.f, perS1 = 0.f;

#pragma unroll
    for (int s = 0; s < SS; ++s){
        const float* bufc = sMsk[s & 1];
        float cmx[4], cmn[4], mC0 = 0.f, mC1 = 0.f;
#pragma unroll
        for (int j = 0; j < 4; ++j){
            const float a = bufc[(pr  )*LW + pc2 + j];
            const float m = bufc[(pr+1)*LW + pc2 + j];
            const float d = bufc[(pr+2)*LW + pc2 + j];
            cmx[j] = fmaxf(fmaxf(a, m), d);
            cmn[j] = fminf(fminf(a, m), d);
            if (j == 1) mC0 = m;
            if (j == 2) mC1 = m;
        }
        const float rng0 = fmaxf(fmaxf(cmx[0],cmx[1]),cmx[2]) - fminf(fminf(cmn[0],cmn[1]),cmn[2]);
        const float rng1 = fmaxf(fmaxf(cmx[1],cmx[2]),cmx[3]) - fminf(fminf(cmn[1],cmn[2]),cmn[3]);
        perS0 += clip01(rng0);
        perS1 += clip01(rng1);

        const float mu = sMean[2*s], mv = sMean[2*s+1];
        const float d0u = fu0-mu, d0v = fv0-mv, d1u = fu1-mu, d1v = fv1-mv;
        const float vm0 = pow045(d0u*d0u + d0v*d0v + 1e-6f);
        const float vm1 = pow045(d1u*d1u + d1v*d1v + 1e-6f);
        numv[s] = vm0*mC0 + vm1*mC1;

        if (s < SS-1){
            // write seg s+1 (loaded 2 iters ago); safe: that buffer was last read
            // at iter s-1 and a barrier separates us from those reads
#pragma unroll
            for (int k = 0; k < 3; ++k) if (hval[k]){ sMsk[(s+1)&1][hli[k]] = pf[k]; occA[k] += pf[k]; }
#pragma unroll
            for (int k = 0; k < 3; ++k) pf[k] = pg[k];
            if (s < SS-3){
#pragma unroll
                for (int k = 0; k < 3; ++k) if (hval[k]) pg[k] = mb[(s+3)*HWP + cgi[k]];
            }
            __syncthreads();
        }
    }

    // occ plane + range
#pragma unroll
    for (int k = 0; k < 3; ++k) if (hval[k]) sOcc[hli[k]] = occA[k];
    __syncthreads();

    float ox[4], on[4];
#pragma unroll
    for (int j = 0; j < 4; ++j){
        const float a = sOcc[(pr  )*LW + pc2 + j];
        const float m = sOcc[(pr+1)*LW + pc2 + j];
        const float d = sOcc[(pr+2)*LW + pc2 + j];
        ox[j] = fmaxf(fmaxf(a, m), d);
        on[j] = fminf(fminf(a, m), d);
    }
    const float org0 = fmaxf(fmaxf(ox[0],ox[1]),ox[2]) - fminf(fminf(on[0],on[1]),on[2]);
    const float org1 = fmaxf(fmaxf(ox[1],ox[2]),ox[3]) - fminf(fminf(on[1],on[2]),on[3]);
    const float bnd0 = clip01(clip01(org0) + perS0);
    const float bnd1 = clip01(clip01(org1) + perS1);

    // Sobel on 3 channels (zero-padded halo)
    float mag0 = 0.f, mag1 = 0.f;
#pragma unroll
    for (int ch = 0; ch < 3; ++ch){
        float top[4], mid[4], bot[4];
#pragma unroll
        for (int j = 0; j < 4; ++j){
            top[j] = sImg[ch][(pr  )*LW + pc2 + j];
            mid[j] = sImg[ch][(pr+1)*LW + pc2 + j];
            bot[j] = sImg[ch][(pr+2)*LW + pc2 + j];
        }
        float colV0 = top[0] + 2.f*mid[0] + bot[0];
        float colV1 = top[1] + 2.f*mid[1] + bot[1];
        float colV2 = top[2] + 2.f*mid[2] + bot[2];
        float colV3 = top[3] + 2.f*mid[3] + bot[3];
        const float gx0 = colV0 - colV2;
        const float gx1 = colV1 - colV3;
        const float gy0 = (top[0] + 2.f*top[1] + top[2]) - (bot[0] + 2.f*bot[1] + bot[2]);
        const float gy1 = (top[1] + 2.f*top[2] + top[3]) - (bot[1] + 2.f*bot[2] + bot[3]);
        mag0 += fabsf(gx0) + fabsf(gy0);
        mag1 += fabsf(gx1) + fabsf(gy1);
    }
    mag0 *= (1.f/3.f); mag1 *= (1.f/3.f);
    const float wgt0 = expf(-10.f * mag0) * (1.f - 0.9f*bnd0);
    const float wgt1 = expf(-10.f * mag1) * (1.f - 0.9f*bnd1);

    // flow smoothness terms with exact border predicates
    const int gh  = h0 + pr;
    const int gw0 = w0 + pc2;
    const int gw1 = gw0 + 1;

    const float lu = sFlo[0][R*LW + pc2],     lv = sFlo[1][R*LW + pc2];
    const float ru = sFlo[0][R*LW + pc2 + 3], rv = sFlo[1][R*LW + pc2 + 3];
    const float uu0 = sFlo[0][(R-1)*LW + pc2+1], uv0 = sFlo[1][(R-1)*LW + pc2+1];
    const float uu1 = sFlo[0][(R-1)*LW + pc2+2], uv1 = sFlo[1][(R-1)*LW + pc2+2];
    const float du0 = sFlo[0][(R+1)*LW + pc2+1], dv0 = sFlo[1][(R+1)*LW + pc2+1];
    const float du1 = sFlo[0][(R+1)*LW + pc2+2], dv1 = sFlo[1][(R+1)*LW + pc2+2];

    float l1x = 0.f, l1y = 0.f, l2x = 0.f, l2y = 0.f;

    if (gw0 >= 1) l1x += 0.5f * (cbn(fu0 - lu) + cbn(fv0 - lv)) * wgt0;
    l1x += 0.5f * (cbn(fu1 - fu0) + cbn(fv1 - fv0)) * wgt1;
    if (gh >= 1){
        l1y += 0.5f * (cbn(fu0 - uu0) + cbn(fv0 - uv0)) * wgt0;
        l1y += 0.5f * (cbn(fu1 - uu1) + cbn(fv1 - uv1)) * wgt1;
    }
    if (gw0 >= 1) l2x += cbn(fu1 - 2.f*fu0 + lu) + cbn(fv1 - 2.f*fv0 + lv);
    if (gw1 <= WW-2) l2x += cbn(ru - 2.f*fu1 + fu0) + cbn(rv - 2.f*fv1 + fv0);
    if (gh >= 1 && gh <= HH-2){
        l2y += cbn(du0 - 2.f*fu0 + uu0) + cbn(dv0 - 2.f*fv0 + uv0);
        l2y += cbn(du1 - 2.f*fu1 + uu1) + cbn(dv1 - 2.f*fv1 + uv1);
    }

    // block reduction of 20 values
    float vals[20];
#pragma unroll
    for (int s = 0; s < SS; ++s) vals[s] = numv[s];
    vals[16] = l1x; vals[17] = l1y; vals[18] = l2x; vals[19] = l2y;

    const int lane = tid & 63, wv = tid >> 6;
#pragma unroll
    for (int i = 0; i < 20; ++i){
        float v = vals[i];
#pragma unroll
        for (int o = 32; o > 0; o >>= 1) v += __shfl_down(v, o, 64);
        if (lane == 0) sRed[wv][i] = v;
    }
    __syncthreads();
    if (tid < 20){
        const float t = sRed[0][tid] + sRed[1][tid] + sRed[2][tid] + sRed[3][tid];
        atomicAdd(ws + WS_ACC + tid, t);
    }
}

// ---------------- finalize ----------------
__global__ void kF(const float* __restrict__ ws, float* __restrict__ out)
{
    __shared__ float sw[SS];
    const int t = threadIdx.x;
    if (t < SS){
        float w = 0.f;
        for (int b = 0; b < BB; ++b) w += fmaxf(ws[WS_MSUM + b*SS + t], 1e-6f);
        sw[t] = w;
    }
    __syncthreads();
    if (t == 0){
        float total = 0.f, tw = 0.f;
        for (int s = 0; s < SS; ++s){
            const float w = sw[s];
            total += (ws[WS_ACC + s] / fmaxf(w, 1e-6f)) * w;
            tw += w;
        }
        const float seg = (tw > 1e-6f) ? (total / tw) : 0.f;
        const float l1 = ws[WS_ACC+16] / (8.f*512.f*511.f) + ws[WS_ACC+17] / (8.f*511.f*512.f);
        const float l2 = ws[WS_ACC+18] / (8.f*2.f*512.f*510.f) + ws[WS_ACC+19] / (8.f*2.f*510.f*512.f);
        out[0] = 0.1f*seg + 0.15f*(l1 + 0.5f*l2);
    }
}

extern "C" void kernel_launch(void* const* d_in, const int* in_sizes, int n_in,
                              void* d_out, int out_size, void* d_ws, size_t ws_size,
                              hipStream_t stream)
{
    (void)in_sizes; (void)n_in; (void)out_size; (void)ws_size;
    const float* flow  = (const float*)d_in[0];
    const float* image = (const float*)d_in[1];
    const float* masks = (const float*)d_in[2];
    float* ws  = (float*)d_ws;
    float* out = (float*)d_out;

    (void)hipMemsetAsync(d_ws, 0, WS_TOTAL * sizeof(float), stream);

    dim3 gA(512, BB);
    kA<<<gA, 256, 0, stream>>>(flow, masks, ws);
    kB<<<1, 256, 0, stream>>>(ws);
    kC<<<4096, 256, 0, stream>>>(flow, image, masks, ws);
    kF<<<1, 64, 0, stream>>>(ws, out);
}

// Round 5
// 517.325 us; speedup vs baseline: 1.2603x; 1.2603x over previous
//
#include <hip/hip_runtime.h>

// Problem constants (fixed by setup_inputs)
#define BB 8
#define SS 16
#define HH 512
#define WW 512
#define HWP (HH*WW)

// kC tiling
#define TH 16
#define TW 32
#define HR 18          // halo rows
#define HC 34          // halo cols
#define NH (HR*HC)     // 612 halo elements
#define LW 35          // padded LDS row stride

// workspace layout (float offsets)
#define WS_MSUM 0      // [8][16]
#define WS_FSUM 128    // [8][16][2]
#define WS_MEAN 384    // [8][16][2]
#define WS_ACC  640    // num_s[16], l1x, l1y, l2x, l2y  (20 floats)
#define WS_TOTAL 660

__device__ __forceinline__ float clip01(float x){ return fminf(fmaxf(x, 0.0f), 1.0f); }
__device__ __forceinline__ float pow045(float v){ return exp2f(0.45f * log2f(v)); }
__device__ __forceinline__ float cbn(float x){ return pow045(x*x + 1e-6f); }

// ---------------- kernel A: mask sums + mask-weighted flow sums ----------------
// One block per (chunk, segment, batch). Each block streams 16384 contiguous
// pixels of ONE mask segment (64 KB run -> DRAM-friendly), plus the flow chunk
// (re-read across the 16 segment-blocks; served by L2/L3). 3 accumulators and
// 12 float4 loads in flight per thread (unroll 4) -> latency hidden by MLP.
__global__ __launch_bounds__(256, 4)
void kA(const float* __restrict__ flow, const float* __restrict__ masks,
        float* __restrict__ ws)
{
    const int c = blockIdx.x;   // 16 chunks of 16384 pixels
    const int s = blockIdx.y;   // 16 segments
    const int b = blockIdx.z;   // 8 batches

    const float* m  = masks + ((size_t)(b*SS + s)) * HWP + c * 16384;
    const float* fU = flow + (size_t)b * 2 * HWP + c * 16384;
    const float* fV = fU + HWP;

    float a0 = 0.f, a1 = 0.f, a2 = 0.f;

#pragma unroll 4
    for (int it = 0; it < 16; ++it){
        const int p = it * 1024 + threadIdx.x * 4;
        const float4 mm = *reinterpret_cast<const float4*>(m  + p);
        const float4 u  = *reinterpret_cast<const float4*>(fU + p);
        const float4 v  = *reinterpret_cast<const float4*>(fV + p);
        a0 += (mm.x + mm.y) + (mm.z + mm.w);
        a1 += mm.x*u.x + mm.y*u.y + mm.z*u.z + mm.w*u.w;
        a2 += mm.x*v.x + mm.y*v.y + mm.z*v.z + mm.w*v.w;
    }

#pragma unroll
    for (int o = 32; o > 0; o >>= 1){
        a0 += __shfl_down(a0, o, 64);
        a1 += __shfl_down(a1, o, 64);
        a2 += __shfl_down(a2, o, 64);
    }

    __shared__ float red[4][3];
    const int lane = threadIdx.x & 63, wv = threadIdx.x >> 6;
    if (lane == 0){ red[wv][0] = a0; red[wv][1] = a1; red[wv][2] = a2; }
    __syncthreads();
    if (threadIdx.x < 3){
        const int i = threadIdx.x;
        const float t = red[0][i] + red[1][i] + red[2][i] + red[3][i];
        if (i == 0) atomicAdd(ws + WS_MSUM + b*SS + s, t);
        else        atomicAdd(ws + WS_FSUM + (b*SS + s)*2 + (i-1), t);
    }
}

// ---------------- kernel B: mean_flow = fsum / max(msum, 1e-6) ----------------
__global__ void kB(float* __restrict__ ws)
{
    const int i = threadIdx.x;            // 256 = 8*16*2
    const int bs = i >> 1;
    const float ms = fmaxf(ws[WS_MSUM + bs], 1e-6f);
    ws[WS_MEAN + i] = ws[WS_FSUM + i] / ms;
}

// ---------------- kernel C: fused boundary/edge/smooth/variance pass ----------------
// Round-3 structure (known-good 151us @ 2 blocks/CU); only change: launch_bounds
// (256,2) -> (256,4) to double resident blocks and hide the per-segment gather
// latency behind the 16 barriers.
__global__ __launch_bounds__(256, 4)
void kC(const float* __restrict__ flow, const float* __restrict__ image,
        const float* __restrict__ masks, float* __restrict__ ws)
{
    const int b  = blockIdx.z;
    const int h0 = blockIdx.y * TH;
    const int w0 = blockIdx.x * TW;
    const int tid = threadIdx.x;

    __shared__ float sImg[3][HR*LW];
    __shared__ float sFlo[2][HR*LW];
    __shared__ float sOcc[HR*LW];
    __shared__ float sMsk[2][HR*LW];
    __shared__ float sMean[2*SS];
    __shared__ float sRed[4][20];

    if (tid < 2*SS) sMean[tid] = ws[WS_MEAN + b*2*SS + tid];

    // halo slot ownership: k=0,1 always valid; k=2 only for tid<100 (612 slots)
    int hli[3], cgi[3]; bool hval[3]; bool hin[3]; int hgi[3];
#pragma unroll
    for (int k = 0; k < 3; ++k){
        const int idx = tid + k*256;
        hval[k] = (k < 2) || (tid < NH - 512);
        const int r = idx / HC, c = idx % HC;
        const int gh = h0 - 1 + r, gw = w0 - 1 + c;
        hli[k] = r*LW + c;
        hin[k] = ((unsigned)gh < (unsigned)HH) && ((unsigned)gw < (unsigned)WW);
        hgi[k] = gh*WW + gw;
        const int ch_ = min(max(gh, 0), HH-1);
        const int cw_ = min(max(gw, 0), WW-1);
        cgi[k] = ch_*WW + cw_;
    }

    const float* img = image + (size_t)b * 3 * HWP;
    const float* flo = flow  + (size_t)b * 2 * HWP;
    const float* mb  = masks + (size_t)b * SS * HWP;

    // image (zero-pad) + flow
#pragma unroll
    for (int k = 0; k < 3; ++k){
        if (hval[k]){
            const bool in = hin[k]; const int gi = hgi[k]; const int li = hli[k];
            sImg[0][li] = in ? img[0*HWP + gi] : 0.f;
            sImg[1][li] = in ? img[1*HWP + gi] : 0.f;
            sImg[2][li] = in ? img[2*HWP + gi] : 0.f;
            sFlo[0][li] = in ? flo[0*HWP + gi] : 0.f;
            sFlo[1][li] = in ? flo[1*HWP + gi] : 0.f;
        }
    }

    float occA[3] = {0.f, 0.f, 0.f};
    float pf[3];

    // prologue: s=0 load+write, s=1 prefetch
#pragma unroll
    for (int k = 0; k < 3; ++k) if (hval[k]) pf[k] = mb[cgi[k]];
#pragma unroll
    for (int k = 0; k < 3; ++k) if (hval[k]){ sMsk[0][hli[k]] = pf[k]; occA[k] += pf[k]; }
#pragma unroll
    for (int k = 0; k < 3; ++k) if (hval[k]) pf[k] = mb[1*HWP + cgi[k]];
    __syncthreads();

    // pixel assignment: 2 horizontally adjacent pixels per thread
    const int pr  = tid >> 4;          // 0..15 tile row
    const int pc2 = (tid & 15) << 1;   // 0,2,..,30 tile col of pixel0
    const int R = pr + 1;
    const float fu0 = sFlo[0][R*LW + pc2+1], fu1 = sFlo[0][R*LW + pc2+2];
    const float fv0 = sFlo[1][R*LW + pc2+1], fv1 = sFlo[1][R*LW + pc2+2];

    float numv[SS];
    float perS0 = 0.f, perS1 = 0.f;

#pragma unroll
    for (int s = 0; s < SS; ++s){
        const float* bufc = sMsk[s & 1];
        float cmx[4], cmn[4], mC0 = 0.f, mC1 = 0.f;
#pragma unroll
        for (int j = 0; j < 4; ++j){
            const float a = bufc[(pr  )*LW + pc2 + j];
            const float m = bufc[(pr+1)*LW + pc2 + j];
            const float d = bufc[(pr+2)*LW + pc2 + j];
            cmx[j] = fmaxf(fmaxf(a, m), d);
            cmn[j] = fminf(fminf(a, m), d);
            if (j == 1) mC0 = m;
            if (j == 2) mC1 = m;
        }
        const float rng0 = fmaxf(fmaxf(cmx[0],cmx[1]),cmx[2]) - fminf(fminf(cmn[0],cmn[1]),cmn[2]);
        const float rng1 = fmaxf(fmaxf(cmx[1],cmx[2]),cmx[3]) - fminf(fminf(cmn[1],cmn[2]),cmn[3]);
        perS0 += clip01(rng0);
        perS1 += clip01(rng1);

        const float mu = sMean[2*s], mv = sMean[2*s+1];
        const float d0u = fu0-mu, d0v = fv0-mv, d1u = fu1-mu, d1v = fv1-mv;
        const float vm0 = pow045(d0u*d0u + d0v*d0v + 1e-6f);
        const float vm1 = pow045(d1u*d1u + d1v*d1v + 1e-6f);
        numv[s] = vm0*mC0 + vm1*mC1;

        if (s < SS-1){
#pragma unroll
            for (int k = 0; k < 3; ++k) if (hval[k]){ sMsk[(s+1)&1][hli[k]] = pf[k]; occA[k] += pf[k]; }
            if (s < SS-2){
#pragma unroll
                for (int k = 0; k < 3; ++k) if (hval[k]) pf[k] = mb[(s+2)*HWP + cgi[k]];
            }
            __syncthreads();
        }
    }

    // occ plane + range
#pragma unroll
    for (int k = 0; k < 3; ++k) if (hval[k]) sOcc[hli[k]] = occA[k];
    __syncthreads();

    float ox[4], on[4];
#pragma unroll
    for (int j = 0; j < 4; ++j){
        const float a = sOcc[(pr  )*LW + pc2 + j];
        const float m = sOcc[(pr+1)*LW + pc2 + j];
        const float d = sOcc[(pr+2)*LW + pc2 + j];
        ox[j] = fmaxf(fmaxf(a, m), d);
        on[j] = fminf(fminf(a, m), d);
    }
    const float org0 = fmaxf(fmaxf(ox[0],ox[1]),ox[2]) - fminf(fminf(on[0],on[1]),on[2]);
    const float org1 = fmaxf(fmaxf(ox[1],ox[2]),ox[3]) - fminf(fminf(on[1],on[2]),on[3]);
    const float bnd0 = clip01(clip01(org0) + perS0);
    const float bnd1 = clip01(clip01(org1) + perS1);

    // Sobel on 3 channels (zero-padded halo)
    float mag0 = 0.f, mag1 = 0.f;
#pragma unroll
    for (int ch = 0; ch < 3; ++ch){
        float top[4], mid[4], bot[4];
#pragma unroll
        for (int j = 0; j < 4; ++j){
            top[j] = sImg[ch][(pr  )*LW + pc2 + j];
            mid[j] = sImg[ch][(pr+1)*LW + pc2 + j];
            bot[j] = sImg[ch][(pr+2)*LW + pc2 + j];
        }
        float colV0 = top[0] + 2.f*mid[0] + bot[0];
        float colV1 = top[1] + 2.f*mid[1] + bot[1];
        float colV2 = top[2] + 2.f*mid[2] + bot[2];
        float colV3 = top[3] + 2.f*mid[3] + bot[3];
        const float gx0 = colV0 - colV2;
        const float gx1 = colV1 - colV3;
        const float gy0 = (top[0] + 2.f*top[1] + top[2]) - (bot[0] + 2.f*bot[1] + bot[2]);
        const float gy1 = (top[1] + 2.f*top[2] + top[3]) - (bot[1] + 2.f*bot[2] + bot[3]);
        mag0 += fabsf(gx0) + fabsf(gy0);
        mag1 += fabsf(gx1) + fabsf(gy1);
    }
    mag0 *= (1.f/3.f); mag1 *= (1.f/3.f);
    const float wgt0 = expf(-10.f * mag0) * (1.f - 0.9f*bnd0);
    const float wgt1 = expf(-10.f * mag1) * (1.f - 0.9f*bnd1);

    // flow smoothness terms with exact border predicates
    const int gh  = h0 + pr;
    const int gw0 = w0 + pc2;
    const int gw1 = gw0 + 1;

    const float lu = sFlo[0][R*LW + pc2],     lv = sFlo[1][R*LW + pc2];
    const float ru = sFlo[0][R*LW + pc2 + 3], rv = sFlo[1][R*LW + pc2 + 3];
    const float uu0 = sFlo[0][(R-1)*LW + pc2+1], uv0 = sFlo[1][(R-1)*LW + pc2+1];
    const float uu1 = sFlo[0][(R-1)*LW + pc2+2], uv1 = sFlo[1][(R-1)*LW + pc2+2];
    const float du0 = sFlo[0][(R+1)*LW + pc2+1], dv0 = sFlo[1][(R+1)*LW + pc2+1];
    const float du1 = sFlo[0][(R+1)*LW + pc2+2], dv1 = sFlo[1][(R+1)*LW + pc2+2];

    float l1x = 0.f, l1y = 0.f, l2x = 0.f, l2y = 0.f;

    if (gw0 >= 1) l1x += 0.5f * (cbn(fu0 - lu) + cbn(fv0 - lv)) * wgt0;
    l1x += 0.5f * (cbn(fu1 - fu0) + cbn(fv1 - fv0)) * wgt1;
    if (gh >= 1){
        l1y += 0.5f * (cbn(fu0 - uu0) + cbn(fv0 - uv0)) * wgt0;
        l1y += 0.5f * (cbn(fu1 - uu1) + cbn(fv1 - uv1)) * wgt1;
    }
    if (gw0 >= 1) l2x += cbn(fu1 - 2.f*fu0 + lu) + cbn(fv1 - 2.f*fv0 + lv);
    if (gw1 <= WW-2) l2x += cbn(ru - 2.f*fu1 + fu0) + cbn(rv - 2.f*fv1 + fv0);
    if (gh >= 1 && gh <= HH-2){
        l2y += cbn(du0 - 2.f*fu0 + uu0) + cbn(dv0 - 2.f*fv0 + uv0);
        l2y += cbn(du1 - 2.f*fu1 + uu1) + cbn(dv1 - 2.f*fv1 + uv1);
    }

    // block reduction of 20 values
    float vals[20];
#pragma unroll
    for (int s = 0; s < SS; ++s) vals[s] = numv[s];
    vals[16] = l1x; vals[17] = l1y; vals[18] = l2x; vals[19] = l2y;

    const int lane = tid & 63, wv = tid >> 6;
#pragma unroll
    for (int i = 0; i < 20; ++i){
        float v = vals[i];
#pragma unroll
        for (int o = 32; o > 0; o >>= 1) v += __shfl_down(v, o, 64);
        if (lane == 0) sRed[wv][i] = v;
    }
    __syncthreads();
    if (tid < 20){
        const float t = sRed[0][tid] + sRed[1][tid] + sRed[2][tid] + sRed[3][tid];
        atomicAdd(ws + WS_ACC + tid, t);
    }
}

// ---------------- finalize ----------------
__global__ void kF(const float* __restrict__ ws, float* __restrict__ out)
{
    __shared__ float sw[SS];
    const int t = threadIdx.x;
    if (t < SS){
        float w = 0.f;
        for (int b = 0; b < BB; ++b) w += fmaxf(ws[WS_MSUM + b*SS + t], 1e-6f);
        sw[t] = w;
    }
    __syncthreads();
    if (t == 0){
        float total = 0.f, tw = 0.f;
        for (int s = 0; s < SS; ++s){
            const float w = sw[s];
            total += (ws[WS_ACC + s] / fmaxf(w, 1e-6f)) * w;
            tw += w;
        }
        const float seg = (tw > 1e-6f) ? (total / tw) : 0.f;
        const float l1 = ws[WS_ACC+16] / (8.f*512.f*511.f) + ws[WS_ACC+17] / (8.f*511.f*512.f);
        const float l2 = ws[WS_ACC+18] / (8.f*2.f*512.f*510.f) + ws[WS_ACC+19] / (8.f*2.f*510.f*512.f);
        out[0] = 0.1f*seg + 0.15f*(l1 + 0.5f*l2);
    }
}

extern "C" void kernel_launch(void* const* d_in, const int* in_sizes, int n_in,
                              void* d_out, int out_size, void* d_ws, size_t ws_size,
                              hipStream_t stream)
{
    (void)in_sizes; (void)n_in; (void)out_size; (void)ws_size;
    const float* flow  = (const float*)d_in[0];
    const float* image = (const float*)d_in[1];
    const float* masks = (const float*)d_in[2];
    float* ws  = (float*)d_ws;
    float* out = (float*)d_out;

    (void)hipMemsetAsync(d_ws, 0, WS_TOTAL * sizeof(float), stream);

    dim3 gA(16, SS, BB);   // (chunk, segment, batch) = 2048 blocks
    kA<<<gA, 256, 0, stream>>>(flow, masks, ws);
    kB<<<1, 256, 0, stream>>>(ws);
    dim3 gC(WW/TW, HH/TH, BB);   // (16, 32, 8)
    kC<<<gC, 256, 0, stream>>>(flow, image, masks, ws);
    kF<<<1, 64, 0, stream>>>(ws, out);
}

// Round 6
// 365.510 us; speedup vs baseline: 1.7838x; 1.4154x over previous
//
#include <hip/hip_runtime.h>

// Problem constants (fixed by setup_inputs)
#define BB 8
#define SS 16
#define HH 512
#define WW 512
#define HWP (HH*WW)

// kC tiling
#define TH 16
#define TW 32
#define HR 18          // halo rows
#define HC 34          // halo cols
#define NH (HR*HC)     // 612 halo elements
#define LW 35          // padded LDS row stride

// workspace layout (float offsets)
#define WS_MSUM 0      // [8][16]
#define WS_FSUM 128    // [8][16][2]
#define WS_MEAN 384    // [8][16][2]
#define WS_ACC  640    // num_s[16], l1x, l1y, l2x, l2y  (20 floats)
#define WS_TOTAL 660

__device__ __forceinline__ float clip01(float x){ return fminf(fmaxf(x, 0.0f), 1.0f); }
__device__ __forceinline__ float pow045(float v){ return exp2f(0.45f * log2f(v)); }
__device__ __forceinline__ float cbn(float x){ return pow045(x*x + 1e-6f); }

// ---------------- kernel A: mask sums + mask-weighted flow sums ----------------
// Each block owns a 4096-pixel chunk; thread t owns 16 pixels (4 float4 groups).
// Flow is loaded ONCE into registers (8 float4). Inner 16-segment loop is fully
// unrolled -> 16 independent mask loads in flight per j-step (MLP by construction).
// No min-blocks launch bound -> compiler free to use ~160 VGPR, no spill squeeze.
__global__ __launch_bounds__(256)
void kA(const float* __restrict__ flow, const float* __restrict__ masks,
        float* __restrict__ ws)
{
    const int b = blockIdx.y;
    const int chunk = blockIdx.x;            // 64 chunks of 4096 pixels
    const int base = chunk * 4096;
    const float* fU = flow + (size_t)b * 2 * HWP + base;
    const float* fV = fU + HWP;
    const float* mb = masks + (size_t)b * SS * HWP + base;

    // flow into registers: 4 groups of float4 per component
    float4 u[4], v[4];
#pragma unroll
    for (int j = 0; j < 4; ++j){
        const int p = (j * 256 + threadIdx.x) * 4;
        u[j] = *reinterpret_cast<const float4*>(fU + p);
        v[j] = *reinterpret_cast<const float4*>(fV + p);
    }

    float am[SS], au[SS], av[SS];
#pragma unroll
    for (int s = 0; s < SS; ++s){ am[s]=0.f; au[s]=0.f; av[s]=0.f; }

#pragma unroll
    for (int j = 0; j < 4; ++j){
        const int p = (j * 256 + threadIdx.x) * 4;
        const float4 uu = u[j], vv = v[j];
#pragma unroll
        for (int s = 0; s < SS; ++s){
            const float4 m = *reinterpret_cast<const float4*>(mb + (size_t)s * HWP + p);
            am[s] += (m.x + m.y) + (m.z + m.w);
            au[s] += m.x*uu.x + m.y*uu.y + m.z*uu.z + m.w*uu.w;
            av[s] += m.x*vv.x + m.y*vv.y + m.z*vv.z + m.w*vv.w;
        }
    }

    // wave reduce each of 48 values
#pragma unroll
    for (int s = 0; s < SS; ++s){
#pragma unroll
        for (int o = 32; o > 0; o >>= 1){
            am[s] += __shfl_down(am[s], o, 64);
            au[s] += __shfl_down(au[s], o, 64);
            av[s] += __shfl_down(av[s], o, 64);
        }
    }
    __shared__ float red[4][3*SS];
    const int lane = threadIdx.x & 63, wv = threadIdx.x >> 6;
    if (lane == 0){
#pragma unroll
        for (int s = 0; s < SS; ++s){
            red[wv][s] = am[s]; red[wv][SS+s] = au[s]; red[wv][2*SS+s] = av[s];
        }
    }
    __syncthreads();
    if (threadIdx.x < 3*SS){
        const int i = threadIdx.x;
        const float t = red[0][i] + red[1][i] + red[2][i] + red[3][i];
        const int s = i % SS, kind = i / SS;
        if (kind == 0) atomicAdd(ws + WS_MSUM + b*SS + s, t);
        else           atomicAdd(ws + WS_FSUM + (b*SS + s)*2 + (kind-1), t);
    }
}

// ---------------- kernel B: mean_flow = fsum / max(msum, 1e-6) ----------------
__global__ void kB(float* __restrict__ ws)
{
    const int i = threadIdx.x;            // 256 = 8*16*2
    const int bs = i >> 1;
    const float ms = fmaxf(ws[WS_MSUM + bs], 1e-6f);
    ws[WS_MEAN + i] = ws[WS_FSUM + i] / ms;
}

// ---------------- kernel C: fused boundary/edge/smooth/variance pass ----------------
// Known-good round-3 configuration: (256,2), VGPR 112, no spill, 151 us.
__global__ __launch_bounds__(256, 2)
void kC(const float* __restrict__ flow, const float* __restrict__ image,
        const float* __restrict__ masks, float* __restrict__ ws)
{
    const int b  = blockIdx.z;
    const int h0 = blockIdx.y * TH;
    const int w0 = blockIdx.x * TW;
    const int tid = threadIdx.x;

    __shared__ float sImg[3][HR*LW];
    __shared__ float sFlo[2][HR*LW];
    __shared__ float sOcc[HR*LW];
    __shared__ float sMsk[2][HR*LW];
    __shared__ float sMean[2*SS];
    __shared__ float sRed[4][20];

    if (tid < 2*SS) sMean[tid] = ws[WS_MEAN + b*2*SS + tid];

    // halo slot ownership: k=0,1 always valid; k=2 only for tid<100 (612 slots)
    int hli[3], cgi[3]; bool hval[3]; bool hin[3]; int hgi[3];
#pragma unroll
    for (int k = 0; k < 3; ++k){
        const int idx = tid + k*256;
        hval[k] = (k < 2) || (tid < NH - 512);
        const int r = idx / HC, c = idx % HC;
        const int gh = h0 - 1 + r, gw = w0 - 1 + c;
        hli[k] = r*LW + c;
        hin[k] = ((unsigned)gh < (unsigned)HH) && ((unsigned)gw < (unsigned)WW);
        hgi[k] = gh*WW + gw;
        const int ch_ = min(max(gh, 0), HH-1);
        const int cw_ = min(max(gw, 0), WW-1);
        cgi[k] = ch_*WW + cw_;
    }

    const float* img = image + (size_t)b * 3 * HWP;
    const float* flo = flow  + (size_t)b * 2 * HWP;
    const float* mb  = masks + (size_t)b * SS * HWP;

    // image (zero-pad) + flow
#pragma unroll
    for (int k = 0; k < 3; ++k){
        if (hval[k]){
            const bool in = hin[k]; const int gi = hgi[k]; const int li = hli[k];
            sImg[0][li] = in ? img[0*HWP + gi] : 0.f;
            sImg[1][li] = in ? img[1*HWP + gi] : 0.f;
            sImg[2][li] = in ? img[2*HWP + gi] : 0.f;
            sFlo[0][li] = in ? flo[0*HWP + gi] : 0.f;
            sFlo[1][li] = in ? flo[1*HWP + gi] : 0.f;
        }
    }

    float occA[3] = {0.f, 0.f, 0.f};
    float pf[3];

    // prologue: s=0 load+write, s=1 prefetch
#pragma unroll
    for (int k = 0; k < 3; ++k) if (hval[k]) pf[k] = mb[cgi[k]];
#pragma unroll
    for (int k = 0; k < 3; ++k) if (hval[k]){ sMsk[0][hli[k]] = pf[k]; occA[k] += pf[k]; }
#pragma unroll
    for (int k = 0; k < 3; ++k) if (hval[k]) pf[k] = mb[1*HWP + cgi[k]];
    __syncthreads();

    // pixel assignment: 2 horizontally adjacent pixels per thread
    const int pr  = tid >> 4;          // 0..15 tile row
    const int pc2 = (tid & 15) << 1;   // 0,2,..,30 tile col of pixel0
    const int R = pr + 1;
    const float fu0 = sFlo[0][R*LW + pc2+1], fu1 = sFlo[0][R*LW + pc2+2];
    const float fv0 = sFlo[1][R*LW + pc2+1], fv1 = sFlo[1][R*LW + pc2+2];

    float numv[SS];
    float perS0 = 0.f, perS1 = 0.f;

#pragma unroll
    for (int s = 0; s < SS; ++s){
        const float* bufc = sMsk[s & 1];
        float cmx[4], cmn[4], mC0 = 0.f, mC1 = 0.f;
#pragma unroll
        for (int j = 0; j < 4; ++j){
            const float a = bufc[(pr  )*LW + pc2 + j];
            const float m = bufc[(pr+1)*LW + pc2 + j];
            const float d = bufc[(pr+2)*LW + pc2 + j];
            cmx[j] = fmaxf(fmaxf(a, m), d);
            cmn[j] = fminf(fminf(a, m), d);
            if (j == 1) mC0 = m;
            if (j == 2) mC1 = m;
        }
        const float rng0 = fmaxf(fmaxf(cmx[0],cmx[1]),cmx[2]) - fminf(fminf(cmn[0],cmn[1]),cmn[2]);
        const float rng1 = fmaxf(fmaxf(cmx[1],cmx[2]),cmx[3]) - fminf(fminf(cmn[1],cmn[2]),cmn[3]);
        perS0 += clip01(rng0);
        perS1 += clip01(rng1);

        const float mu = sMean[2*s], mv = sMean[2*s+1];
        const float d0u = fu0-mu, d0v = fv0-mv, d1u = fu1-mu, d1v = fv1-mv;
        const float vm0 = pow045(d0u*d0u + d0v*d0v + 1e-6f);
        const float vm1 = pow045(d1u*d1u + d1v*d1v + 1e-6f);
        numv[s] = vm0*mC0 + vm1*mC1;

        if (s < SS-1){
#pragma unroll
            for (int k = 0; k < 3; ++k) if (hval[k]){ sMsk[(s+1)&1][hli[k]] = pf[k]; occA[k] += pf[k]; }
            if (s < SS-2){
#pragma unroll
                for (int k = 0; k < 3; ++k) if (hval[k]) pf[k] = mb[(s+2)*HWP + cgi[k]];
            }
            __syncthreads();
        }
    }

    // occ plane + range
#pragma unroll
    for (int k = 0; k < 3; ++k) if (hval[k]) sOcc[hli[k]] = occA[k];
    __syncthreads();

    float ox[4], on[4];
#pragma unroll
    for (int j = 0; j < 4; ++j){
        const float a = sOcc[(pr  )*LW + pc2 + j];
        const float m = sOcc[(pr+1)*LW + pc2 + j];
        const float d = sOcc[(pr+2)*LW + pc2 + j];
        ox[j] = fmaxf(fmaxf(a, m), d);
        on[j] = fminf(fminf(a, m), d);
    }
    const float org0 = fmaxf(fmaxf(ox[0],ox[1]),ox[2]) - fminf(fminf(on[0],on[1]),on[2]);
    const float org1 = fmaxf(fmaxf(ox[1],ox[2]),ox[3]) - fminf(fminf(on[1],on[2]),on[3]);
    const float bnd0 = clip01(clip01(org0) + perS0);
    const float bnd1 = clip01(clip01(org1) + perS1);

    // Sobel on 3 channels (zero-padded halo)
    float mag0 = 0.f, mag1 = 0.f;
#pragma unroll
    for (int ch = 0; ch < 3; ++ch){
        float top[4], mid[4], bot[4];
#pragma unroll
        for (int j = 0; j < 4; ++j){
            top[j] = sImg[ch][(pr  )*LW + pc2 + j];
            mid[j] = sImg[ch][(pr+1)*LW + pc2 + j];
            bot[j] = sImg[ch][(pr+2)*LW + pc2 + j];
        }
        float colV0 = top[0] + 2.f*mid[0] + bot[0];
        float colV1 = top[1] + 2.f*mid[1] + bot[1];
        float colV2 = top[2] + 2.f*mid[2] + bot[2];
        float colV3 = top[3] + 2.f*mid[3] + bot[3];
        const float gx0 = colV0 - colV2;
        const float gx1 = colV1 - colV3;
        const float gy0 = (top[0] + 2.f*top[1] + top[2]) - (bot[0] + 2.f*bot[1] + bot[2]);
        const float gy1 = (top[1] + 2.f*top[2] + top[3]) - (bot[1] + 2.f*bot[2] + bot[3]);
        mag0 += fabsf(gx0) + fabsf(gy0);
        mag1 += fabsf(gx1) + fabsf(gy1);
    }
    mag0 *= (1.f/3.f); mag1 *= (1.f/3.f);
    const float wgt0 = expf(-10.f * mag0) * (1.f - 0.9f*bnd0);
    const float wgt1 = expf(-10.f * mag1) * (1.f - 0.9f*bnd1);

    // flow smoothness terms with exact border predicates
    const int gh  = h0 + pr;
    const int gw0 = w0 + pc2;
    const int gw1 = gw0 + 1;

    const float lu = sFlo[0][R*LW + pc2],     lv = sFlo[1][R*LW + pc2];
    const float ru = sFlo[0][R*LW + pc2 + 3], rv = sFlo[1][R*LW + pc2 + 3];
    const float uu0 = sFlo[0][(R-1)*LW + pc2+1], uv0 = sFlo[1][(R-1)*LW + pc2+1];
    const float uu1 = sFlo[0][(R-1)*LW + pc2+2], uv1 = sFlo[1][(R-1)*LW + pc2+2];
    const float du0 = sFlo[0][(R+1)*LW + pc2+1], dv0 = sFlo[1][(R+1)*LW + pc2+1];
    const float du1 = sFlo[0][(R+1)*LW + pc2+2], dv1 = sFlo[1][(R+1)*LW + pc2+2];

    float l1x = 0.f, l1y = 0.f, l2x = 0.f, l2y = 0.f;

    if (gw0 >= 1) l1x += 0.5f * (cbn(fu0 - lu) + cbn(fv0 - lv)) * wgt0;
    l1x += 0.5f * (cbn(fu1 - fu0) + cbn(fv1 - fv0)) * wgt1;
    if (gh >= 1){
        l1y += 0.5f * (cbn(fu0 - uu0) + cbn(fv0 - uv0)) * wgt0;
        l1y += 0.5f * (cbn(fu1 - uu1) + cbn(fv1 - uv1)) * wgt1;
    }
    if (gw0 >= 1) l2x += cbn(fu1 - 2.f*fu0 + lu) + cbn(fv1 - 2.f*fv0 + lv);
    if (gw1 <= WW-2) l2x += cbn(ru - 2.f*fu1 + fu0) + cbn(rv - 2.f*fv1 + fv0);
    if (gh >= 1 && gh <= HH-2){
        l2y += cbn(du0 - 2.f*fu0 + uu0) + cbn(dv0 - 2.f*fv0 + uv0);
        l2y += cbn(du1 - 2.f*fu1 + uu1) + cbn(dv1 - 2.f*fv1 + uv1);
    }

    // block reduction of 20 values
    float vals[20];
#pragma unroll
    for (int s = 0; s < SS; ++s) vals[s] = numv[s];
    vals[16] = l1x; vals[17] = l1y; vals[18] = l2x; vals[19] = l2y;

    const int lane = tid & 63, wv = tid >> 6;
#pragma unroll
    for (int i = 0; i < 20; ++i){
        float v = vals[i];
#pragma unroll
        for (int o = 32; o > 0; o >>= 1) v += __shfl_down(v, o, 64);
        if (lane == 0) sRed[wv][i] = v;
    }
    __syncthreads();
    if (tid < 20){
        const float t = sRed[0][tid] + sRed[1][tid] + sRed[2][tid] + sRed[3][tid];
        atomicAdd(ws + WS_ACC + tid, t);
    }
}

// ---------------- finalize ----------------
__global__ void kF(const float* __restrict__ ws, float* __restrict__ out)
{
    __shared__ float sw[SS];
    const int t = threadIdx.x;
    if (t < SS){
        float w = 0.f;
        for (int b = 0; b < BB; ++b) w += fmaxf(ws[WS_MSUM + b*SS + t], 1e-6f);
        sw[t] = w;
    }
    __syncthreads();
    if (t == 0){
        float total = 0.f, tw = 0.f;
        for (int s = 0; s < SS; ++s){
            const float w = sw[s];
            total += (ws[WS_ACC + s] / fmaxf(w, 1e-6f)) * w;
            tw += w;
        }
        const float seg = (tw > 1e-6f) ? (total / tw) : 0.f;
        const float l1 = ws[WS_ACC+16] / (8.f*512.f*511.f) + ws[WS_ACC+17] / (8.f*511.f*512.f);
        const float l2 = ws[WS_ACC+18] / (8.f*2.f*512.f*510.f) + ws[WS_ACC+19] / (8.f*2.f*510.f*512.f);
        out[0] = 0.1f*seg + 0.15f*(l1 + 0.5f*l2);
    }
}

extern "C" void kernel_launch(void* const* d_in, const int* in_sizes, int n_in,
                              void* d_out, int out_size, void* d_ws, size_t ws_size,
                              hipStream_t stream)
{
    (void)in_sizes; (void)n_in; (void)out_size; (void)ws_size;
    const float* flow  = (const float*)d_in[0];
    const float* image = (const float*)d_in[1];
    const float* masks = (const float*)d_in[2];
    float* ws  = (float*)d_ws;
    float* out = (float*)d_out;

    (void)hipMemsetAsync(d_ws, 0, WS_TOTAL * sizeof(float), stream);

    dim3 gA(64, BB);   // 512 blocks, 4096 px each
    kA<<<gA, 256, 0, stream>>>(flow, masks, ws);
    kB<<<1, 256, 0, stream>>>(ws);
    dim3 gC(WW/TW, HH/TH, BB);   // (16, 32, 8)
    kC<<<gC, 256, 0, stream>>>(flow, image, masks, ws);
    kF<<<1, 64, 0, stream>>>(ws, out);
}